// Round 7
// baseline (2417.414 us; speedup 1.0000x reference)
//
#include <hip/hip_runtime.h>
#include <hip/hip_bf16.h>

#define NGRAPH 128
#define NTOT   65536
#define NE     262144
#define EPG    2048
#define HC     256

typedef __hip_bfloat16 bf16;

// ------- fused 4-way GEMM: Y_s[nc][256] = X[nc][F] @ W_s[F][256] + b_s -----
template<int F>
__global__ __launch_bounds__(256)
void gemm_qkvs_kernel(const float* __restrict__ X,
                      const float* __restrict__ W0, const float* __restrict__ B0,
                      const float* __restrict__ W1, const float* __restrict__ B1,
                      const float* __restrict__ W2, const float* __restrict__ B2,
                      const float* __restrict__ W3, const float* __restrict__ B3,
                      float* __restrict__ Y, long ystride)
{
  const int s = blockIdx.y;
  const float* __restrict__ W = (s==0)?W0:(s==1)?W1:(s==2)?W2:W3;
  const float* __restrict__ Bb= (s==0)?B0:(s==1)?B1:(s==2)?B2:B3;
  float* __restrict__ Yo = Y + (long)s*ystride;

  __shared__ __align__(16) float XsT[F][36];
  const int tid = threadIdx.x;
  const long r0 = (long)blockIdx.x * 32;
  for (int idx = tid; idx < 32*F; idx += 256){
    int r = idx / F;
    int f = idx - r*F;
    XsT[f][r] = X[(r0 + r)*F + f];
  }
  __syncthreads();
  float acc[32];
#pragma unroll
  for (int r = 0; r < 32; ++r) acc[r] = 0.f;
  for (int f = 0; f < F; ++f){
    float w = W[f*HC + tid];
    const float4* xs4 = (const float4*)(&XsT[f][0]);
#pragma unroll
    for (int r4 = 0; r4 < 8; ++r4){
      float4 xv = xs4[r4];
      acc[r4*4+0] = fmaf(xv.x, w, acc[r4*4+0]);
      acc[r4*4+1] = fmaf(xv.y, w, acc[r4*4+1]);
      acc[r4*4+2] = fmaf(xv.z, w, acc[r4*4+2]);
      acc[r4*4+3] = fmaf(xv.w, w, acc[r4*4+3]);
    }
  }
  float bb = Bb[tid];
#pragma unroll
  for (int r = 0; r < 32; ++r)
    Yo[(r0 + r)*HC + tid] = acc[r] + bb;
}

// ------- M[g][j] = sum_c Wq[g][h*64+c]*We[f][h*64+c],  j=(h<<5)|f ----------
// Row g==F holds the bias-combine: sum_c bq[h*64+c]*We[f][h*64+c].
__global__ void mcomb_kernel(const float* __restrict__ Wq,
                             const float* __restrict__ bq,
                             const float* __restrict__ We,
                             int F, float* __restrict__ M)
{
  int id = blockIdx.x*256 + threadIdx.x;
  if (id >= (F+1)*128) return;
  int g = id >> 7;
  int j = id & 127;
  int h = j >> 5, f = j & 31;
  const float* row = (g < F) ? (Wq + (long)g*HC) : bq;
  const float* wr  = We + (long)f*HC + h*64;
  float s = 0.f;
#pragma unroll
  for (int c = 0; c < 64; ++c) s = fmaf(row[h*64 + c], wr[c], s);
  M[id] = s;
}

// ------- qwe[nc][128] = X[nc][F] @ M[F][128] + M[F] (bias row) -------------
template<int F>
__global__ __launch_bounds__(128)
void qwe_gemm_kernel(const float* __restrict__ X, const float* __restrict__ M,
                     float* __restrict__ qwe)
{
  __shared__ __align__(16) float XsT[F][36];
  const int tid = threadIdx.x;
  const long r0 = (long)blockIdx.x * 32;
  for (int idx = tid; idx < 32*F; idx += 128){
    int r = idx / F;
    int f = idx - r*F;
    XsT[f][r] = X[(r0 + r)*F + f];
  }
  __syncthreads();
  float acc[32];
#pragma unroll
  for (int r = 0; r < 32; ++r) acc[r] = 0.f;
  for (int f = 0; f < F; ++f){
    float w = M[f*128 + tid];
    const float4* xs4 = (const float4*)(&XsT[f][0]);
#pragma unroll
    for (int r4 = 0; r4 < 8; ++r4){
      float4 xv = xs4[r4];
      acc[r4*4+0] = fmaf(xv.x, w, acc[r4*4+0]);
      acc[r4*4+1] = fmaf(xv.y, w, acc[r4*4+1]);
      acc[r4*4+2] = fmaf(xv.z, w, acc[r4*4+2]);
      acc[r4*4+3] = fmaf(xv.w, w, acc[r4*4+3]);
    }
  }
  float bb = M[F*128 + tid];
#pragma unroll
  for (int r = 0; r < 32; ++r)
    qwe[(r0 + r)*128 + tid] = acc[r] + bb;
}

// ---------------- Deterministic per-graph CSR build ------------------------
__global__ __launch_bounds__(256)
void csr_build_kernel(const int* __restrict__ dstA, int npgLoc,
                      int* __restrict__ eids, int* __restrict__ rowptr,
                      int* __restrict__ deg)
{
  __shared__ int dloc[2048];
  __shared__ int ord[2048];
  __shared__ int cnt[512];
  __shared__ int base[512];
  const int g = blockIdx.x, tid = threadIdx.x;
  const int ebase = g*2048;
  const int nbase = g*npgLoc;
  for (int e = tid; e < 2048; e += 256){
    int d = dstA[ebase + e];
    dloc[e] = (d >= 0) ? (d - nbase) : -1;
  }
  for (int d = tid; d < npgLoc; d += 256) cnt[d] = 0;
  __syncthreads();
  for (int r = 0; r < 8; ++r){
    const int e = r*256 + tid;
    const int d = dloc[e];
    int rk = -1;
    if (d >= 0){
      rk = cnt[d];
      for (int u = r*256; u < e; ++u)
        rk += (dloc[u] == d);
    }
    ord[e] = rk;
    __syncthreads();
    if (d >= 0) atomicAdd(&cnt[d], 1);
    __syncthreads();
  }
  if (tid == 0){
    int run = 0;
    for (int d = 0; d < npgLoc; ++d){ base[d] = run; run += cnt[d]; }
  }
  __syncthreads();
  for (int e = tid; e < 2048; e += 256){
    int d = dloc[e];
    if (d >= 0) eids[ebase + base[d] + ord[e]] = ebase + e;
  }
  for (int d = tid; d < npgLoc; d += 256){
    rowptr[nbase + d] = ebase + base[d];
    deg   [nbase + d] = cnt[d];
  }
}

// ---------------- attn v3: one block per node, one wave per head -----------
// lane = channel within head (c = h*64+lane). Score uses precomputed qwe:
//   alpha = (q.k + ea.qwe)/8.  Output e-term deferred: wsum_f += p*ea_f,
//   epilogue adds wsum@We. Beta gate reduced across heads via LDS.
__global__ __launch_bounds__(256)
void attn_kernel(int nodeOff,
                 const float* q, const float* __restrict__ k,
                 const float* __restrict__ v, const float* __restrict__ skip,
                 const float* __restrict__ qwe,
                 const int* __restrict__ rowptr, const int* __restrict__ deg,
                 const int* __restrict__ eids, const int* __restrict__ srcA,
                 const float* __restrict__ EA, const float* __restrict__ We,
                 const float* __restrict__ Wb, float* xout)
{
  const int lane = threadIdx.x & 63;
  const int h    = threadIdx.x >> 6;      // head = wave
  const int il   = blockIdx.x;            // local node row
  const int i    = nodeOff + il;          // global node id
  const int c    = h*64 + lane;           // channel

  const float qv = q[(long)il*HC + c];
  const float qw = (lane < 32) ? qwe[(long)il*128 + h*32 + lane] : 0.f;

  const int p0 = rowptr[i];
  const int dg = deg[i];
  int e_l = 0, s_l = 0;
  if (lane < dg){ e_l = eids[p0 + lane]; s_l = srcA[e_l] - nodeOff; }

  float m = -__builtin_inff();
  float den = 0.f, acc = 0.f, wsum = 0.f;

  for (int t = 0; t < dg; ++t){
    int e, s;
    if (t < 64){ e = __shfl(e_l, t); s = __shfl(s_l, t); }
    else { e = eids[p0 + t]; s = srcA[e] - nodeOff; }
    float ea = (lane < 32) ? EA[(long)e*32 + lane] : 0.f;
    float kk = k[(long)s*HC + c];
    float vv = v[(long)s*HC + c];
    float part = fmaf(qv, kk, ea*qw);
    part += __shfl_xor(part, 1);
    part += __shfl_xor(part, 2);
    part += __shfl_xor(part, 4);
    part += __shfl_xor(part, 8);
    part += __shfl_xor(part, 16);
    part += __shfl_xor(part, 32);
    float alpha = part * 0.125f;
    float nm  = fmaxf(m, alpha);
    float scl = __expf(m - nm);
    float p   = __expf(alpha - nm);
    den  = den*scl + p;
    acc  = fmaf(acc,  scl, p*vv);
    wsum = fmaf(wsum, scl, p*ea);
    m = nm;
  }

  // epilogue: e-term via wsum @ We (this head's 32 rows)
  float ecorr = 0.f;
#pragma unroll
  for (int f = 0; f < 32; ++f)
    ecorr = fmaf(__shfl(wsum, f), We[f*HC + c], ecorr);
  float inv = 1.f / fmaxf(den, 1e-16f);
  float o = (acc + ecorr) * inv;

  float xr = skip[(long)il*HC + c];
  float tp = o*Wb[c] + xr*Wb[HC + c] + (o - xr)*Wb[2*HC + c];
  tp += __shfl_xor(tp, 1);
  tp += __shfl_xor(tp, 2);
  tp += __shfl_xor(tp, 4);
  tp += __shfl_xor(tp, 8);
  tp += __shfl_xor(tp, 16);
  tp += __shfl_xor(tp, 32);
  __shared__ float tsh[4];
  if (lane == 0) tsh[h] = tp;
  __syncthreads();
  float tt = tsh[0] + tsh[1] + tsh[2] + tsh[3];
  float beta = 1.f / (1.f + __expf(-tt));
  xout[(long)il*HC + c] = beta*xr + (1.f - beta)*o;
}

// ------------- y = relu(Xa[nc][256] @ Wt[256][64] + bt) --------------------
__global__ __launch_bounds__(256)
void gemm_wt_kernel(const float* __restrict__ Xa, const float* __restrict__ Wt,
                    const float* __restrict__ bt, float* __restrict__ y)
{
  const int wave = threadIdx.x >> 6;
  const int lane = threadIdx.x & 63;
  const long row = (long)blockIdx.x * 4 + wave;
  const float* xr = Xa + row*HC;
  float acc = 0.f;
#pragma unroll 8
  for (int f = 0; f < HC; ++f)
    acc = fmaf(xr[f], Wt[f*64 + lane], acc);
  acc += bt[lane];
  y[row*64 + lane] = fmaxf(acc, 0.f);
}

// ------------- BN stats: 256-block grid-stride partials --------------------
__global__ __launch_bounds__(256)
void bn_stats_kernel(const float* __restrict__ y, long total4,
                     float* __restrict__ psum, float* __restrict__ psq)
{
  __shared__ float s1[256][4], s2[256][4];
  const int tid = threadIdx.x;
  float a0=0,a1=0,a2=0,a3=0,b0=0,b1=0,b2=0,b3=0;
  const float4* y4 = (const float4*)y;
  for (long j = (long)blockIdx.x*256 + tid; j < total4; j += 65536){
    float4 v = y4[j];
    a0 += v.x; b0 += v.x*v.x;
    a1 += v.y; b1 += v.y*v.y;
    a2 += v.z; b2 += v.z*v.z;
    a3 += v.w; b3 += v.w*v.w;
  }
  s1[tid][0]=a0; s1[tid][1]=a1; s1[tid][2]=a2; s1[tid][3]=a3;
  s2[tid][0]=b0; s2[tid][1]=b1; s2[tid][2]=b2; s2[tid][3]=b3;
  __syncthreads();
  if (tid < 64){
    int t0 = tid >> 2, comp = tid & 3;
    float sa = 0.f, sb = 0.f;
#pragma unroll
    for (int kk = 0; kk < 16; ++kk){
      sa += s1[t0 + 16*kk][comp];
      sb += s2[t0 + 16*kk][comp];
    }
    psum[(long)blockIdx.x*64 + tid] = sa;
    psq [(long)blockIdx.x*64 + tid] = sb;
  }
}

__global__ void bn_finalize_kernel(const float* __restrict__ psum,
                                   const float* __restrict__ psq,
                                   float n_f, float* musd)
{
  __shared__ float s1[4][64], s2[4][64];
  const int col = threadIdx.x & 63;
  const int part = threadIdx.x >> 6;
  float a = 0.f, b = 0.f;
  for (int j = part; j < 256; j += 4){
    a += psum[(long)j*64 + col];
    b += psq [(long)j*64 + col];
  }
  s1[part][col] = a; s2[part][col] = b;
  __syncthreads();
  if (threadIdx.x < 64){
    int c = threadIdx.x;
    float sa = s1[0][c] + s1[1][c] + s1[2][c] + s1[3][c];
    float sb = s2[0][c] + s2[1][c] + s2[2][c] + s2[3][c];
    float mu = sa / n_f;
    float var = sb / n_f - mu*mu;
    musd[c] = mu;
    musd[64 + c] = rsqrtf(var + 1e-5f);
  }
}

__global__ void bn_apply_kernel(float* y, const float* __restrict__ musd,
                                const float* __restrict__ g,
                                const float* __restrict__ b, long total)
{
  long i4 = ((long)blockIdx.x * 256 + threadIdx.x) * 4;
  if (i4 >= total) return;
  int c0 = (int)(i4 & 63);
  float4 yv = *(float4*)&y[i4];
  yv.x = (yv.x - musd[c0+0]) * musd[64+c0+0] * g[c0+0] + b[c0+0];
  yv.y = (yv.y - musd[c0+1]) * musd[64+c0+1] * g[c0+1] + b[c0+1];
  yv.z = (yv.z - musd[c0+2]) * musd[64+c0+2] * g[c0+2] + b[c0+2];
  yv.w = (yv.w - musd[c0+3]) * musd[64+c0+3] * g[c0+3] + b[c0+3];
  *(float4*)&y[i4] = yv;
}

// ---------------- TopK pooling: exact rank (ties by lower index) -----------
__global__ __launch_bounds__(256)
void topk_kernel(const float* __restrict__ x, const float* __restrict__ pw,
                 float* __restrict__ x2, int* __restrict__ newidx,
                 int npg, int kkeep)
{
  __shared__ float sc[512];
  __shared__ float wS[64];
  const int g = blockIdx.x, tid = threadIdx.x;
  if (tid < 64) wS[tid] = pw[tid];
  __syncthreads();
  float nrm = 0.f;
#pragma unroll
  for (int c = 0; c < 64; ++c) nrm += wS[c]*wS[c];
  nrm = sqrtf(nrm);
  for (int il = tid; il < npg; il += 256){
    const float* xr = x + (long)(g*npg + il)*64;
    float d = 0.f;
    for (int c = 0; c < 64; ++c) d = fmaf(xr[c], wS[c], d);
    sc[il] = tanhf(d / nrm);
  }
  __syncthreads();
  for (int il = tid; il < npg; il += 256){
    float si = sc[il];
    int r = 0;
    for (int j = 0; j < npg; ++j){
      float sj = sc[j];
      r += (sj > si) || (sj == si && j < il);
    }
    int gi = g*npg + il;
    if (r < kkeep){
      int npos = g*kkeep + r;
      newidx[gi] = npos;
      const float4* xr4 = (const float4*)(x + (long)gi*64);
      float4* xo4 = (float4*)(x2 + (long)npos*64);
#pragma unroll
      for (int c4 = 0; c4 < 16; ++c4){
        float4 xv = xr4[c4];
        xo4[c4] = make_float4(xv.x*si, xv.y*si, xv.z*si, xv.w*si);
      }
    } else {
      newidx[gi] = -1;
    }
  }
}

__global__ void remap_kernel(const int* __restrict__ src0, const int* __restrict__ dst0,
                             const int* __restrict__ newidx,
                             int* __restrict__ src2, int* __restrict__ dst2)
{
  int e = blockIdx.x * 256 + threadIdx.x;
  int ns = newidx[src0[e]];
  int nd = newidx[dst0[e]];
  bool ok = (ns >= 0) && (nd >= 0);
  src2[e] = ok ? ns : 0;
  dst2[e] = ok ? nd : -1;
}

// ---------------- Graph readout: max + mean (f32 output) -------------------
__global__ void gpool_kernel(const float* __restrict__ x2, int kkeep,
                             float* grep0, float* out, int mode)
{
  const int g = blockIdx.x, c = threadIdx.x;   // 64 threads
  float mx = -__builtin_inff(), s = 0.f;
  for (int j = 0; j < kkeep; ++j){
    float vv = x2[((long)g*kkeep + j)*64 + c];
    mx = fmaxf(mx, vv);
    s += vv;
  }
  float mean = s / (float)kkeep;
  if (mode == 0){
    grep0[g*128 + c] = mx;
    grep0[g*128 + 64 + c] = mean;
  } else {
    out[g*128 + c]      = grep0[g*128 + c] + mx;
    out[g*128 + 64 + c] = grep0[g*128 + 64 + c] + mean;
  }
}

// ---------------------------------------------------------------------------
extern "C" void kernel_launch(void* const* d_in, const int* in_sizes, int n_in,
                              void* d_out, int out_size, void* d_ws, size_t ws_size,
                              hipStream_t stream)
{
  const float* x_in = (const float*)d_in[0];
  const float* EA   = (const float*)d_in[1];
  const int*   eidx = (const int*)d_in[2];
  const int*   src0 = eidx;
  const int*   dst0 = eidx + NE;

  const float* Wq1    = (const float*)d_in[4];
  const float* bq1    = (const float*)d_in[5];
  const float* Wk1    = (const float*)d_in[6];
  const float* bk1    = (const float*)d_in[7];
  const float* Wv1    = (const float*)d_in[8];
  const float* bv1    = (const float*)d_in[9];
  const float* We1    = (const float*)d_in[10];
  const float* Wskip1 = (const float*)d_in[11];
  const float* bskip1 = (const float*)d_in[12];
  const float* Wbeta1 = (const float*)d_in[13];
  const float* Wt1    = (const float*)d_in[14];
  const float* bt1    = (const float*)d_in[15];
  const float* bng1   = (const float*)d_in[16];
  const float* bnb1   = (const float*)d_in[17];
  const float* WqL    = (const float*)d_in[18];
  const float* bqL    = (const float*)d_in[19];
  const float* WkL    = (const float*)d_in[20];
  const float* bkL    = (const float*)d_in[21];
  const float* WvL    = (const float*)d_in[22];
  const float* bvL    = (const float*)d_in[23];
  const float* WeL    = (const float*)d_in[24];
  const float* WskipL = (const float*)d_in[25];
  const float* bskipL = (const float*)d_in[26];
  const float* WbetaL = (const float*)d_in[27];
  const float* WtL    = (const float*)d_in[28];
  const float* btL    = (const float*)d_in[29];
  const float* bngL   = (const float*)d_in[30];
  const float* bnbL   = (const float*)d_in[31];
  const float* pw0    = (const float*)d_in[32];
  const float* pw2    = (const float*)d_in[33];

  // ---- adaptive chunking: q/k/v/skip (n x 256) + qwe (n x 128) -----------
  const size_t FIXED = 33554432ull;
  int chunks = 1;
  while (chunks < 32 && 9ull*(67108864ull/chunks)/2 + FIXED > ws_size)
    chunks <<= 1;
  const int gpc = NGRAPH / chunks;           // graphs per chunk
  const size_t C = 67108864ull / chunks;     // bytes per 256-wide buffer
  const long CF = (long)(C / 4);             // floats per 256-wide buffer

  char* wsb = (char*)d_ws;
  float* qb   = (float*)(wsb);
  float* kb   = (float*)(wsb + C);
  float* vb   = (float*)(wsb + 2*C);
  float* sk   = (float*)(wsb + 3*C);
  float* qweb = (float*)(wsb + 4*C);         // C/2 bytes
  char* p = wsb + 4*C + C/2;
  auto alloc = [&](size_t bytes){ char* r = p; p += (bytes + 255) & ~255ull; return r; };
  float* y      = (float*)alloc(16777216ull);
  float* x2     = (float*)alloc(8388608ull);
  float* ps     = (float*)alloc(65536ull);
  float* pq     = (float*)alloc(65536ull);
  float* musd   = (float*)alloc(4096ull);
  float* grep0  = (float*)alloc(65536ull);
  float* Mbuf   = (float*)alloc(66304ull);   // (F+1)*128 floats, F<=128
  int* newidx   = (int*)alloc(262144ull);
  int* src2     = (int*)alloc(1048576ull);
  int* dst2     = (int*)alloc(1048576ull);
  int* eidsA    = (int*)alloc(1048576ull);
  int* rowptrA  = (int*)alloc(262144ull);
  int* degA     = (int*)alloc(262144ull);
  int* eidsB    = (int*)alloc(1048576ull);
  int* rowptrB  = (int*)alloc(131072ull);
  int* degB     = (int*)alloc(131072ull);

  // -------- CSR for full topology --------
  csr_build_kernel<<<NGRAPH, 256, 0, stream>>>(dst0, 512, eidsA, rowptrA, degA);

  // -------- Layer 1 (F=128, n=65536, npg=512) --------
  {
    const int npg = 512, n = NTOT;
    mcomb_kernel<<<(129*128 + 255)/256, 256, 0, stream>>>(Wq1, bq1, We1, 128, Mbuf);
    for (int c = 0; c < chunks; ++c){
      const int nOff = c * gpc * npg;
      const int nc   = gpc * npg;
      const float* Xc = x_in + (long)nOff * 128;
      dim3 grid(nc/32, 4);
      gemm_qkvs_kernel<128><<<grid, 256, 0, stream>>>(
          Xc, Wq1, bq1, Wk1, bk1, Wv1, bv1, Wskip1, bskip1, qb, CF);
      qwe_gemm_kernel<128><<<nc/32, 128, 0, stream>>>(Xc, Mbuf, qweb);
      attn_kernel<<<nc, 256, 0, stream>>>(nOff, qb, kb, vb, sk, qweb,
          rowptrA, degA, eidsA, src0, EA, We1, Wbeta1, qb);
      gemm_wt_kernel<<<nc/4, 256, 0, stream>>>(qb, Wt1, bt1, y + (long)nOff*64);
    }
    bn_stats_kernel<<<256, 256, 0, stream>>>(y, (long)n*16, ps, pq);
    bn_finalize_kernel<<<1, 256, 0, stream>>>(ps, pq, (float)n, musd);
    bn_apply_kernel<<<n/16, 256, 0, stream>>>(y, musd, bng1, bnb1, (long)n*64);
  }

  // -------- Loop layers i = 0..2 --------
  for (int i = 0; i < 3; ++i){
    const int n   = (i == 0) ? NTOT : NTOT/2;
    const int npg = (i == 0) ? 512 : 256;
    const float* xin = (i == 0) ? y : ((i == 1) ? x2 : y);
    const int* rp = (i == 0) ? rowptrA : rowptrB;
    const int* dgp= (i == 0) ? degA    : degB;
    const int* ei = (i == 0) ? eidsA   : eidsB;
    const int* sA = (i == 0) ? src0    : src2;
    const float* Wq_ = WqL + (long)i*64*256;  const float* bq_ = bqL + i*256;
    const float* Wk_ = WkL + (long)i*64*256;  const float* bk_ = bkL + i*256;
    const float* Wv_ = WvL + (long)i*64*256;  const float* bv_ = bvL + i*256;
    const float* Ws_ = WskipL + (long)i*64*256; const float* bs_ = bskipL + i*256;
    const float* We_ = WeL + (long)i*32*256;
    const float* Wb_ = WbetaL + i*768;
    const float* Wt_ = WtL + (long)i*256*64;  const float* bt_ = btL + i*64;
    const float* g_  = bngL + i*64;           const float* b_  = bnbL + i*64;

    mcomb_kernel<<<(65*128 + 255)/256, 256, 0, stream>>>(Wq_, bq_, We_, 64, Mbuf);
    for (int c = 0; c < chunks; ++c){
      const int nOff = c * gpc * npg;
      const int nc   = gpc * npg;
      const float* Xc = xin + (long)nOff * 64;
      dim3 grid(nc/32, 4);
      gemm_qkvs_kernel<64><<<grid, 256, 0, stream>>>(
          Xc, Wq_, bq_, Wk_, bk_, Wv_, bv_, Ws_, bs_, qb, CF);
      qwe_gemm_kernel<64><<<nc/32, 128, 0, stream>>>(Xc, Mbuf, qweb);
      attn_kernel<<<nc, 256, 0, stream>>>(nOff, qb, kb, vb, sk, qweb,
          rp, dgp, ei, sA, EA, We_, Wb_, qb);
      gemm_wt_kernel<<<nc/4, 256, 0, stream>>>(qb, Wt_, bt_, y + (long)nOff*64);
    }
    bn_stats_kernel<<<256, 256, 0, stream>>>(y, (long)n*16, ps, pq);
    bn_finalize_kernel<<<1, 256, 0, stream>>>(ps, pq, (float)n, musd);
    bn_apply_kernel<<<n/16, 256, 0, stream>>>(y, musd, g_, b_, (long)n*64);

    if (i == 0){
      topk_kernel<<<NGRAPH, 256, 0, stream>>>(y, pw0, x2, newidx, 512, 256);
      remap_kernel<<<NE/256, 256, 0, stream>>>(src0, dst0, newidx, src2, dst2);
      csr_build_kernel<<<NGRAPH, 256, 0, stream>>>(dst2, 256, eidsB, rowptrB, degB);
      gpool_kernel<<<NGRAPH, 64, 0, stream>>>(x2, 256, grep0, (float*)d_out, 0);
    } else if (i == 2){
      topk_kernel<<<NGRAPH, 256, 0, stream>>>(y, pw2, x2, newidx, 256, 128);
      gpool_kernel<<<NGRAPH, 64, 0, stream>>>(x2, 128, grep0, (float*)d_out, 1);
    }
  }

  (void)in_sizes; (void)n_in; (void)out_size; (void)ws_size;
}

// Round 8
// 1832.662 us; speedup vs baseline: 1.3191x; 1.3191x over previous
//
#include <hip/hip_runtime.h>
#include <hip/hip_bf16.h>

#define NGRAPH 128
#define NTOT   65536
#define NE     262144
#define EPG    2048
#define HC     256

typedef __hip_bfloat16 bf16;

__device__ __forceinline__ float4 f4fma(float a, float4 b, float4 c){
  return make_float4(fmaf(a,b.x,c.x), fmaf(a,b.y,c.y), fmaf(a,b.z,c.z), fmaf(a,b.w,c.w));
}
__device__ __forceinline__ float4 f4add(float4 a, float4 b){
  return make_float4(a.x+b.x, a.y+b.y, a.z+b.z, a.w+b.w);
}

// ------- fused 4-way GEMM: Y_s[nc][256] = X[nc][F] @ W_s[F][256] + b_s -----
// 32 rows x 256 cols per block; thread = 8 rows x 4 cols (32 accs).
template<int F>
__global__ __launch_bounds__(256)
void gemm_qkvs_kernel(const float* __restrict__ X,
                      const float* __restrict__ W0, const float* __restrict__ B0,
                      const float* __restrict__ W1, const float* __restrict__ B1,
                      const float* __restrict__ W2, const float* __restrict__ B2,
                      const float* __restrict__ W3, const float* __restrict__ B3,
                      float* __restrict__ Y, long ystride)
{
  const int s = blockIdx.y;
  const float* __restrict__ W = (s==0)?W0:(s==1)?W1:(s==2)?W2:W3;
  const float* __restrict__ Bb= (s==0)?B0:(s==1)?B1:(s==2)?B2:B3;
  float* __restrict__ Yo = Y + (long)s*ystride;

  __shared__ __align__(16) float XsT[F][36];    // 36*4=144B rows (16B aligned)
  const int tid  = threadIdx.x;
  const int tcol = tid & 63;        // cols 4*tcol..+3
  const int trow = tid >> 6;        // rows 8*trow..+7
  const long r0 = (long)blockIdx.x * 32;
  for (int idx = tid; idx < 32*F; idx += 256){
    int r = idx / F;
    int f = idx - r*F;
    XsT[f][r] = X[(r0 + r)*F + f];
  }
  __syncthreads();
  float4 acc[8];
#pragma unroll
  for (int r = 0; r < 8; ++r) acc[r] = make_float4(0.f,0.f,0.f,0.f);
  for (int f = 0; f < F; ++f){
    float4 w = *(const float4*)(&W[f*HC + 4*tcol]);
    float xs[8];
    *(float4*)&xs[0] = *(const float4*)(&XsT[f][8*trow]);
    *(float4*)&xs[4] = *(const float4*)(&XsT[f][8*trow + 4]);
#pragma unroll
    for (int r = 0; r < 8; ++r) acc[r] = f4fma(xs[r], w, acc[r]);
  }
  float4 bb = *(const float4*)(&Bb[4*tcol]);
#pragma unroll
  for (int r = 0; r < 8; ++r)
    *(float4*)(&Yo[(r0 + 8*trow + r)*HC + 4*tcol]) = f4add(acc[r], bb);
}

// ------- M[g][j] = sum_c Wq[g][h*64+c]*We[f][h*64+c],  j=(h<<5)|f ----------
// Row g==F is the bias-combine row.
__global__ void mcomb_kernel(const float* __restrict__ Wq,
                             const float* __restrict__ bq,
                             const float* __restrict__ We,
                             int F, float* __restrict__ M)
{
  int id = blockIdx.x*256 + threadIdx.x;
  if (id >= (F+1)*128) return;
  int g = id >> 7;
  int j = id & 127;
  int h = j >> 5, f = j & 31;
  const float* row = (g < F) ? (Wq + (long)g*HC) : bq;
  const float* wr  = We + (long)f*HC + h*64;
  float s = 0.f;
#pragma unroll
  for (int c = 0; c < 64; ++c) s = fmaf(row[h*64 + c], wr[c], s);
  M[id] = s;
}

// ------- qwe[nc][128] = X[nc][F] @ M[F][128] + M[F] --------------------------
// 64 rows x 128 cols per block; thread = 8 rows x 4 cols.
template<int F>
__global__ __launch_bounds__(256)
void qwe_gemm_kernel(const float* __restrict__ X, const float* __restrict__ M,
                     float* __restrict__ qwe)
{
  __shared__ __align__(16) float XsT[F][68];    // 68*4=272B rows (16B aligned)
  const int tid  = threadIdx.x;
  const int tcol = tid & 31;        // cols 4*tcol..+3
  const int trow = tid >> 5;        // rows 8*trow..+7 (8 groups -> 64 rows)
  const long r0 = (long)blockIdx.x * 64;
  for (int idx = tid; idx < 64*F; idx += 256){
    int r = idx / F;
    int f = idx - r*F;
    XsT[f][r] = X[(r0 + r)*F + f];
  }
  __syncthreads();
  float4 acc[8];
#pragma unroll
  for (int r = 0; r < 8; ++r) acc[r] = make_float4(0.f,0.f,0.f,0.f);
  for (int f = 0; f < F; ++f){
    float4 w = *(const float4*)(&M[f*128 + 4*tcol]);
    float xs[8];
    *(float4*)&xs[0] = *(const float4*)(&XsT[f][8*trow]);
    *(float4*)&xs[4] = *(const float4*)(&XsT[f][8*trow + 4]);
#pragma unroll
    for (int r = 0; r < 8; ++r) acc[r] = f4fma(xs[r], w, acc[r]);
  }
  float4 bb = *(const float4*)(&M[F*128 + 4*tcol]);
#pragma unroll
  for (int r = 0; r < 8; ++r)
    *(float4*)(&qwe[(r0 + 8*trow + r)*128 + 4*tcol]) = f4add(acc[r], bb);
}

// ---------------- Deterministic per-graph CSR build ------------------------
__global__ __launch_bounds__(256)
void csr_build_kernel(const int* __restrict__ dstA, int npgLoc,
                      int* __restrict__ eids, int* __restrict__ rowptr,
                      int* __restrict__ deg)
{
  __shared__ int dloc[2048];
  __shared__ int ord[2048];
  __shared__ int cnt[512];
  __shared__ int base[512];
  const int g = blockIdx.x, tid = threadIdx.x;
  const int ebase = g*2048;
  const int nbase = g*npgLoc;
  for (int e = tid; e < 2048; e += 256){
    int d = dstA[ebase + e];
    dloc[e] = (d >= 0) ? (d - nbase) : -1;
  }
  for (int d = tid; d < npgLoc; d += 256) cnt[d] = 0;
  __syncthreads();
  for (int r = 0; r < 8; ++r){
    const int e = r*256 + tid;
    const int d = dloc[e];
    int rk = -1;
    if (d >= 0){
      rk = cnt[d];
      for (int u = r*256; u < e; ++u)
        rk += (dloc[u] == d);
    }
    ord[e] = rk;
    __syncthreads();
    if (d >= 0) atomicAdd(&cnt[d], 1);
    __syncthreads();
  }
  if (tid == 0){
    int run = 0;
    for (int d = 0; d < npgLoc; ++d){ base[d] = run; run += cnt[d]; }
  }
  __syncthreads();
  for (int e = tid; e < 2048; e += 256){
    int d = dloc[e];
    if (d >= 0) eids[ebase + base[d] + ord[e]] = ebase + e;
  }
  for (int d = tid; d < npgLoc; d += 256){
    rowptr[nbase + d] = ebase + base[d];
    deg   [nbase + d] = cnt[d];
  }
}

// ---------------- attn: one block per node, one wave per head --------------
__global__ __launch_bounds__(256)
void attn_kernel(int nodeOff,
                 const float* q, const float* __restrict__ k,
                 const float* __restrict__ v, const float* __restrict__ skip,
                 const float* __restrict__ qwe,
                 const int* __restrict__ rowptr, const int* __restrict__ deg,
                 const int* __restrict__ eids, const int* __restrict__ srcA,
                 const float* __restrict__ EA, const float* __restrict__ We,
                 const float* __restrict__ Wb, float* xout)
{
  const int lane = threadIdx.x & 63;
  const int h    = threadIdx.x >> 6;      // head = wave
  const int il   = blockIdx.x;            // local node row
  const int i    = nodeOff + il;          // global node id
  const int c    = h*64 + lane;           // channel

  const float qv = q[(long)il*HC + c];
  const float qw = (lane < 32) ? qwe[(long)il*128 + h*32 + lane] : 0.f;

  const int p0 = rowptr[i];
  const int dg = deg[i];
  int e_l = 0, s_l = 0;
  if (lane < dg){ e_l = eids[p0 + lane]; s_l = srcA[e_l] - nodeOff; }

  float m = -__builtin_inff();
  float den = 0.f, acc = 0.f, wsum = 0.f;

  for (int t = 0; t < dg; ++t){
    int e, s;
    if (t < 64){ e = __shfl(e_l, t); s = __shfl(s_l, t); }
    else { e = eids[p0 + t]; s = srcA[e] - nodeOff; }
    float ea = (lane < 32) ? EA[(long)e*32 + lane] : 0.f;
    float kk = k[(long)s*HC + c];
    float vv = v[(long)s*HC + c];
    float part = fmaf(qv, kk, ea*qw);
    part += __shfl_xor(part, 1);
    part += __shfl_xor(part, 2);
    part += __shfl_xor(part, 4);
    part += __shfl_xor(part, 8);
    part += __shfl_xor(part, 16);
    part += __shfl_xor(part, 32);
    float alpha = part * 0.125f;
    float nm  = fmaxf(m, alpha);
    float scl = __expf(m - nm);
    float p   = __expf(alpha - nm);
    den  = den*scl + p;
    acc  = fmaf(acc,  scl, p*vv);
    wsum = fmaf(wsum, scl, p*ea);
    m = nm;
  }

  float ecorr = 0.f;
#pragma unroll
  for (int f = 0; f < 32; ++f)
    ecorr = fmaf(__shfl(wsum, f), We[f*HC + c], ecorr);
  float inv = 1.f / fmaxf(den, 1e-16f);
  float o = (acc + ecorr) * inv;

  float xr = skip[(long)il*HC + c];
  float tp = o*Wb[c] + xr*Wb[HC + c] + (o - xr)*Wb[2*HC + c];
  tp += __shfl_xor(tp, 1);
  tp += __shfl_xor(tp, 2);
  tp += __shfl_xor(tp, 4);
  tp += __shfl_xor(tp, 8);
  tp += __shfl_xor(tp, 16);
  tp += __shfl_xor(tp, 32);
  __shared__ float tsh[4];
  if (lane == 0) tsh[h] = tp;
  __syncthreads();
  float tt = tsh[0] + tsh[1] + tsh[2] + tsh[3];
  float beta = 1.f / (1.f + __expf(-tt));
  xout[(long)il*HC + c] = beta*xr + (1.f - beta)*o;
}

// ------------- y = relu(Xa[nc][256] @ Wt[256][64] + bt) --------------------
// 128 rows x 64 cols per block; thread = 8 rows x 4 cols; K staged 4x64.
__global__ __launch_bounds__(256)
void gemm_wt_kernel(const float* __restrict__ Xa, const float* __restrict__ Wt,
                    const float* __restrict__ bt, float* __restrict__ y)
{
  __shared__ __align__(16) float XsT[64][132];  // 132*4=528B rows (16B aligned)
  const int tid  = threadIdx.x;
  const int tcol = tid & 15;        // cols 4*tcol..+3
  const int trow = tid >> 4;        // rows 8*trow..+7 (16 groups -> 128 rows)
  const long r0 = (long)blockIdx.x * 128;
  float4 acc[8];
#pragma unroll
  for (int r = 0; r < 8; ++r) acc[r] = make_float4(0.f,0.f,0.f,0.f);
  for (int kc = 0; kc < 4; ++kc){
    for (int idx = tid; idx < 128*64; idx += 256){
      int r = idx >> 6;
      int f = idx & 63;
      XsT[f][r] = Xa[(r0 + r)*HC + kc*64 + f];
    }
    __syncthreads();
    for (int f = 0; f < 64; ++f){
      float4 w = *(const float4*)(&Wt[(kc*64 + f)*64 + 4*tcol]);
      float xs[8];
      *(float4*)&xs[0] = *(const float4*)(&XsT[f][8*trow]);
      *(float4*)&xs[4] = *(const float4*)(&XsT[f][8*trow + 4]);
#pragma unroll
      for (int r = 0; r < 8; ++r) acc[r] = f4fma(xs[r], w, acc[r]);
    }
    __syncthreads();
  }
  float4 bb = *(const float4*)(&bt[4*tcol]);
#pragma unroll
  for (int r = 0; r < 8; ++r){
    float4 o = f4add(acc[r], bb);
    o.x = fmaxf(o.x, 0.f); o.y = fmaxf(o.y, 0.f);
    o.z = fmaxf(o.z, 0.f); o.w = fmaxf(o.w, 0.f);
    *(float4*)(&y[(r0 + 8*trow + r)*64 + 4*tcol]) = o;
  }
}

// ------------- BN stats: 256-block grid-stride partials --------------------
__global__ __launch_bounds__(256)
void bn_stats_kernel(const float* __restrict__ y, long total4,
                     float* __restrict__ psum, float* __restrict__ psq)
{
  __shared__ float s1[256][4], s2[256][4];
  const int tid = threadIdx.x;
  float a0=0,a1=0,a2=0,a3=0,b0=0,b1=0,b2=0,b3=0;
  const float4* y4 = (const float4*)y;
  for (long j = (long)blockIdx.x*256 + tid; j < total4; j += 65536){
    float4 v = y4[j];
    a0 += v.x; b0 += v.x*v.x;
    a1 += v.y; b1 += v.y*v.y;
    a2 += v.z; b2 += v.z*v.z;
    a3 += v.w; b3 += v.w*v.w;
  }
  s1[tid][0]=a0; s1[tid][1]=a1; s1[tid][2]=a2; s1[tid][3]=a3;
  s2[tid][0]=b0; s2[tid][1]=b1; s2[tid][2]=b2; s2[tid][3]=b3;
  __syncthreads();
  if (tid < 64){
    int t0 = tid >> 2, comp = tid & 3;
    float sa = 0.f, sb = 0.f;
#pragma unroll
    for (int kk = 0; kk < 16; ++kk){
      sa += s1[t0 + 16*kk][comp];
      sb += s2[t0 + 16*kk][comp];
    }
    psum[(long)blockIdx.x*64 + tid] = sa;
    psq [(long)blockIdx.x*64 + tid] = sb;
  }
}

__global__ void bn_finalize_kernel(const float* __restrict__ psum,
                                   const float* __restrict__ psq,
                                   float n_f, float* musd)
{
  __shared__ float s1[4][64], s2[4][64];
  const int col = threadIdx.x & 63;
  const int part = threadIdx.x >> 6;
  float a = 0.f, b = 0.f;
  for (int j = part; j < 256; j += 4){
    a += psum[(long)j*64 + col];
    b += psq [(long)j*64 + col];
  }
  s1[part][col] = a; s2[part][col] = b;
  __syncthreads();
  if (threadIdx.x < 64){
    int c = threadIdx.x;
    float sa = s1[0][c] + s1[1][c] + s1[2][c] + s1[3][c];
    float sb = s2[0][c] + s2[1][c] + s2[2][c] + s2[3][c];
    float mu = sa / n_f;
    float var = sb / n_f - mu*mu;
    musd[c] = mu;
    musd[64 + c] = rsqrtf(var + 1e-5f);
  }
}

__global__ void bn_apply_kernel(float* y, const float* __restrict__ musd,
                                const float* __restrict__ g,
                                const float* __restrict__ b, long total)
{
  long i4 = ((long)blockIdx.x * 256 + threadIdx.x) * 4;
  if (i4 >= total) return;
  int c0 = (int)(i4 & 63);
  float4 yv = *(float4*)&y[i4];
  yv.x = (yv.x - musd[c0+0]) * musd[64+c0+0] * g[c0+0] + b[c0+0];
  yv.y = (yv.y - musd[c0+1]) * musd[64+c0+1] * g[c0+1] + b[c0+1];
  yv.z = (yv.z - musd[c0+2]) * musd[64+c0+2] * g[c0+2] + b[c0+2];
  yv.w = (yv.w - musd[c0+3]) * musd[64+c0+3] * g[c0+3] + b[c0+3];
  *(float4*)&y[i4] = yv;
}

// ---------------- TopK pooling: exact rank (ties by lower index) -----------
__global__ __launch_bounds__(256)
void topk_kernel(const float* __restrict__ x, const float* __restrict__ pw,
                 float* __restrict__ x2, int* __restrict__ newidx,
                 int npg, int kkeep)
{
  __shared__ float sc[512];
  __shared__ float wS[64];
  const int g = blockIdx.x, tid = threadIdx.x;
  if (tid < 64) wS[tid] = pw[tid];
  __syncthreads();
  float nrm = 0.f;
#pragma unroll
  for (int c = 0; c < 64; ++c) nrm += wS[c]*wS[c];
  nrm = sqrtf(nrm);
  for (int il = tid; il < npg; il += 256){
    const float* xr = x + (long)(g*npg + il)*64;
    float d = 0.f;
    for (int c = 0; c < 64; ++c) d = fmaf(xr[c], wS[c], d);
    sc[il] = tanhf(d / nrm);
  }
  __syncthreads();
  for (int il = tid; il < npg; il += 256){
    float si = sc[il];
    int r = 0;
    for (int j = 0; j < npg; ++j){
      float sj = sc[j];
      r += (sj > si) || (sj == si && j < il);
    }
    int gi = g*npg + il;
    if (r < kkeep){
      int npos = g*kkeep + r;
      newidx[gi] = npos;
      const float4* xr4 = (const float4*)(x + (long)gi*64);
      float4* xo4 = (float4*)(x2 + (long)npos*64);
#pragma unroll
      for (int c4 = 0; c4 < 16; ++c4){
        float4 xv = xr4[c4];
        xo4[c4] = make_float4(xv.x*si, xv.y*si, xv.z*si, xv.w*si);
      }
    } else {
      newidx[gi] = -1;
    }
  }
}

__global__ void remap_kernel(const int* __restrict__ src0, const int* __restrict__ dst0,
                             const int* __restrict__ newidx,
                             int* __restrict__ src2, int* __restrict__ dst2)
{
  int e = blockIdx.x * 256 + threadIdx.x;
  int ns = newidx[src0[e]];
  int nd = newidx[dst0[e]];
  bool ok = (ns >= 0) && (nd >= 0);
  src2[e] = ok ? ns : 0;
  dst2[e] = ok ? nd : -1;
}

// ---------------- Graph readout: max + mean (f32 output) -------------------
__global__ void gpool_kernel(const float* __restrict__ x2, int kkeep,
                             float* grep0, float* out, int mode)
{
  const int g = blockIdx.x, c = threadIdx.x;   // 64 threads
  float mx = -__builtin_inff(), s = 0.f;
  for (int j = 0; j < kkeep; ++j){
    float vv = x2[((long)g*kkeep + j)*64 + c];
    mx = fmaxf(mx, vv);
    s += vv;
  }
  float mean = s / (float)kkeep;
  if (mode == 0){
    grep0[g*128 + c] = mx;
    grep0[g*128 + 64 + c] = mean;
  } else {
    out[g*128 + c]      = grep0[g*128 + c] + mx;
    out[g*128 + 64 + c] = grep0[g*128 + 64 + c] + mean;
  }
}

// ---------------------------------------------------------------------------
extern "C" void kernel_launch(void* const* d_in, const int* in_sizes, int n_in,
                              void* d_out, int out_size, void* d_ws, size_t ws_size,
                              hipStream_t stream)
{
  const float* x_in = (const float*)d_in[0];
  const float* EA   = (const float*)d_in[1];
  const int*   eidx = (const int*)d_in[2];
  const int*   src0 = eidx;
  const int*   dst0 = eidx + NE;

  const float* Wq1    = (const float*)d_in[4];
  const float* bq1    = (const float*)d_in[5];
  const float* Wk1    = (const float*)d_in[6];
  const float* bk1    = (const float*)d_in[7];
  const float* Wv1    = (const float*)d_in[8];
  const float* bv1    = (const float*)d_in[9];
  const float* We1    = (const float*)d_in[10];
  const float* Wskip1 = (const float*)d_in[11];
  const float* bskip1 = (const float*)d_in[12];
  const float* Wbeta1 = (const float*)d_in[13];
  const float* Wt1    = (const float*)d_in[14];
  const float* bt1    = (const float*)d_in[15];
  const float* bng1   = (const float*)d_in[16];
  const float* bnb1   = (const float*)d_in[17];
  const float* WqL    = (const float*)d_in[18];
  const float* bqL    = (const float*)d_in[19];
  const float* WkL    = (const float*)d_in[20];
  const float* bkL    = (const float*)d_in[21];
  const float* WvL    = (const float*)d_in[22];
  const float* bvL    = (const float*)d_in[23];
  const float* WeL    = (const float*)d_in[24];
  const float* WskipL = (const float*)d_in[25];
  const float* bskipL = (const float*)d_in[26];
  const float* WbetaL = (const float*)d_in[27];
  const float* WtL    = (const float*)d_in[28];
  const float* btL    = (const float*)d_in[29];
  const float* bngL   = (const float*)d_in[30];
  const float* bnbL   = (const float*)d_in[31];
  const float* pw0    = (const float*)d_in[32];
  const float* pw2    = (const float*)d_in[33];

  // ---- adaptive chunking: q/k/v/skip (n x 256) + qwe (n x 128) -----------
  const size_t FIXED = 33554432ull;
  int chunks = 1;
  while (chunks < 32 && 9ull*(67108864ull/chunks)/2 + FIXED > ws_size)
    chunks <<= 1;
  const int gpc = NGRAPH / chunks;           // graphs per chunk
  const size_t C = 67108864ull / chunks;     // bytes per 256-wide buffer
  const long CF = (long)(C / 4);             // floats per 256-wide buffer

  char* wsb = (char*)d_ws;
  float* qb   = (float*)(wsb);
  float* kb   = (float*)(wsb + C);
  float* vb   = (float*)(wsb + 2*C);
  float* sk   = (float*)(wsb + 3*C);
  float* qweb = (float*)(wsb + 4*C);         // C/2 bytes
  char* p = wsb + 4*C + C/2;
  auto alloc = [&](size_t bytes){ char* r = p; p += (bytes + 255) & ~255ull; return r; };
  float* y      = (float*)alloc(16777216ull);
  float* x2     = (float*)alloc(8388608ull);
  float* ps     = (float*)alloc(65536ull);
  float* pq     = (float*)alloc(65536ull);
  float* musd   = (float*)alloc(4096ull);
  float* grep0  = (float*)alloc(65536ull);
  float* Mbuf   = (float*)alloc(66304ull);   // (F+1)*128 floats, F<=128
  int* newidx   = (int*)alloc(262144ull);
  int* src2     = (int*)alloc(1048576ull);
  int* dst2     = (int*)alloc(1048576ull);
  int* eidsA    = (int*)alloc(1048576ull);
  int* rowptrA  = (int*)alloc(262144ull);
  int* degA     = (int*)alloc(262144ull);
  int* eidsB    = (int*)alloc(1048576ull);
  int* rowptrB  = (int*)alloc(131072ull);
  int* degB     = (int*)alloc(131072ull);

  // -------- CSR for full topology --------
  csr_build_kernel<<<NGRAPH, 256, 0, stream>>>(dst0, 512, eidsA, rowptrA, degA);

  // -------- Layer 1 (F=128, n=65536, npg=512) --------
  {
    const int npg = 512, n = NTOT;
    mcomb_kernel<<<(129*128 + 255)/256, 256, 0, stream>>>(Wq1, bq1, We1, 128, Mbuf);
    for (int c = 0; c < chunks; ++c){
      const int nOff = c * gpc * npg;
      const int nc   = gpc * npg;
      const float* Xc = x_in + (long)nOff * 128;
      dim3 grid(nc/32, 4);
      gemm_qkvs_kernel<128><<<grid, 256, 0, stream>>>(
          Xc, Wq1, bq1, Wk1, bk1, Wv1, bv1, Wskip1, bskip1, qb, CF);
      qwe_gemm_kernel<128><<<nc/64, 256, 0, stream>>>(Xc, Mbuf, qweb);
      attn_kernel<<<nc, 256, 0, stream>>>(nOff, qb, kb, vb, sk, qweb,
          rowptrA, degA, eidsA, src0, EA, We1, Wbeta1, qb);
      gemm_wt_kernel<<<nc/128, 256, 0, stream>>>(qb, Wt1, bt1, y + (long)nOff*64);
    }
    bn_stats_kernel<<<256, 256, 0, stream>>>(y, (long)n*16, ps, pq);
    bn_finalize_kernel<<<1, 256, 0, stream>>>(ps, pq, (float)n, musd);
    bn_apply_kernel<<<n/16, 256, 0, stream>>>(y, musd, bng1, bnb1, (long)n*64);
  }

  // -------- Loop layers i = 0..2 --------
  for (int i = 0; i < 3; ++i){
    const int n   = (i == 0) ? NTOT : NTOT/2;
    const int npg = (i == 0) ? 512 : 256;
    const float* xin = (i == 0) ? y : ((i == 1) ? x2 : y);
    const int* rp = (i == 0) ? rowptrA : rowptrB;
    const int* dgp= (i == 0) ? degA    : degB;
    const int* ei = (i == 0) ? eidsA   : eidsB;
    const int* sA = (i == 0) ? src0    : src2;
    const float* Wq_ = WqL + (long)i*64*256;  const float* bq_ = bqL + i*256;
    const float* Wk_ = WkL + (long)i*64*256;  const float* bk_ = bkL + i*256;
    const float* Wv_ = WvL + (long)i*64*256;  const float* bv_ = bvL + i*256;
    const float* Ws_ = WskipL + (long)i*64*256; const float* bs_ = bskipL + i*256;
    const float* We_ = WeL + (long)i*32*256;
    const float* Wb_ = WbetaL + i*768;
    const float* Wt_ = WtL + (long)i*256*64;  const float* bt_ = btL + i*64;
    const float* g_  = bngL + i*64;           const float* b_  = bnbL + i*64;

    mcomb_kernel<<<(65*128 + 255)/256, 256, 0, stream>>>(Wq_, bq_, We_, 64, Mbuf);
    for (int c = 0; c < chunks; ++c){
      const int nOff = c * gpc * npg;
      const int nc   = gpc * npg;
      const float* Xc = xin + (long)nOff * 64;
      dim3 grid(nc/32, 4);
      gemm_qkvs_kernel<64><<<grid, 256, 0, stream>>>(
          Xc, Wq_, bq_, Wk_, bk_, Wv_, bv_, Ws_, bs_, qb, CF);
      qwe_gemm_kernel<64><<<nc/64, 256, 0, stream>>>(Xc, Mbuf, qweb);
      attn_kernel<<<nc, 256, 0, stream>>>(nOff, qb, kb, vb, sk, qweb,
          rp, dgp, ei, sA, EA, We_, Wb_, qb);
      gemm_wt_kernel<<<nc/128, 256, 0, stream>>>(qb, Wt_, bt_, y + (long)nOff*64);
    }
    bn_stats_kernel<<<256, 256, 0, stream>>>(y, (long)n*16, ps, pq);
    bn_finalize_kernel<<<1, 256, 0, stream>>>(ps, pq, (float)n, musd);
    bn_apply_kernel<<<n/16, 256, 0, stream>>>(y, musd, g_, b_, (long)n*64);

    if (i == 0){
      topk_kernel<<<NGRAPH, 256, 0, stream>>>(y, pw0, x2, newidx, 512, 256);
      remap_kernel<<<NE/256, 256, 0, stream>>>(src0, dst0, newidx, src2, dst2);
      csr_build_kernel<<<NGRAPH, 256, 0, stream>>>(dst2, 256, eidsB, rowptrB, degB);
      gpool_kernel<<<NGRAPH, 64, 0, stream>>>(x2, 256, grep0, (float*)d_out, 0);
    } else if (i == 2){
      topk_kernel<<<NGRAPH, 256, 0, stream>>>(y, pw2, x2, newidx, 256, 128);
      gpool_kernel<<<NGRAPH, 64, 0, stream>>>(x2, 128, grep0, (float*)d_out, 1);
    }
  }

  (void)in_sizes; (void)n_in; (void)out_size; (void)ws_size;
}

// Round 10
// 1572.009 us; speedup vs baseline: 1.5378x; 1.1658x over previous
//
#include <hip/hip_runtime.h>
#include <hip/hip_bf16.h>

#define NGRAPH 128
#define NTOT   65536
#define NE     262144
#define EPG    2048
#define HC     256

typedef __hip_bfloat16 bf16;

__device__ __forceinline__ float4 f4fma(float a, float4 b, float4 c){
  return make_float4(fmaf(a,b.x,c.x), fmaf(a,b.y,c.y), fmaf(a,b.z,c.z), fmaf(a,b.w,c.w));
}
__device__ __forceinline__ float4 f4add(float4 a, float4 b){
  return make_float4(a.x+b.x, a.y+b.y, a.z+b.z, a.w+b.w);
}

// ------- fused 4-way GEMM: Y_s[nc][256] = X[nc][F] @ W_s[F][256] + b_s -----
// 32 rows x 256 cols per block; thread = 8 rows x 4 cols (32 accs).
template<int F>
__global__ __launch_bounds__(256)
void gemm_qkvs_kernel(const float* __restrict__ X,
                      const float* __restrict__ W0, const float* __restrict__ B0,
                      const float* __restrict__ W1, const float* __restrict__ B1,
                      const float* __restrict__ W2, const float* __restrict__ B2,
                      const float* __restrict__ W3, const float* __restrict__ B3,
                      float* __restrict__ Y, long ystride)
{
  const int s = blockIdx.y;
  const float* __restrict__ W = (s==0)?W0:(s==1)?W1:(s==2)?W2:W3;
  const float* __restrict__ Bb= (s==0)?B0:(s==1)?B1:(s==2)?B2:B3;
  float* __restrict__ Yo = Y + (long)s*ystride;

  __shared__ __align__(16) float XsT[F][36];
  const int tid  = threadIdx.x;
  const int tcol = tid & 63;
  const int trow = tid >> 6;
  const long r0 = (long)blockIdx.x * 32;
  for (int idx = tid; idx < 32*F; idx += 256){
    int r = idx / F;
    int f = idx - r*F;
    XsT[f][r] = X[(r0 + r)*F + f];
  }
  __syncthreads();
  float4 acc[8];
#pragma unroll
  for (int r = 0; r < 8; ++r) acc[r] = make_float4(0.f,0.f,0.f,0.f);
  for (int f = 0; f < F; ++f){
    float4 w = *(const float4*)(&W[f*HC + 4*tcol]);
    float xs[8];
    *(float4*)&xs[0] = *(const float4*)(&XsT[f][8*trow]);
    *(float4*)&xs[4] = *(const float4*)(&XsT[f][8*trow + 4]);
#pragma unroll
    for (int r = 0; r < 8; ++r) acc[r] = f4fma(xs[r], w, acc[r]);
  }
  float4 bb = *(const float4*)(&Bb[4*tcol]);
#pragma unroll
  for (int r = 0; r < 8; ++r)
    *(float4*)(&Yo[(r0 + 8*trow + r)*HC + 4*tcol]) = f4add(acc[r], bb);
}

// ------- M[g][j] = sum_c Wq[g][h*64+c]*We[f][h*64+c],  j=(h<<5)|f ----------
__global__ void mcomb_kernel(const float* __restrict__ Wq,
                             const float* __restrict__ bq,
                             const float* __restrict__ We,
                             int F, float* __restrict__ M)
{
  int id = blockIdx.x*256 + threadIdx.x;
  if (id >= (F+1)*128) return;
  int g = id >> 7;
  int j = id & 127;
  int h = j >> 5, f = j & 31;
  const float* row = (g < F) ? (Wq + (long)g*HC) : bq;
  const float* wr  = We + (long)f*HC + h*64;
  float s = 0.f;
#pragma unroll
  for (int c = 0; c < 64; ++c) s = fmaf(row[h*64 + c], wr[c], s);
  M[id] = s;
}

// ------- qwe[nc][128] = X[nc][F] @ M[F][128] + M[F] ------------------------
template<int F>
__global__ __launch_bounds__(256)
void qwe_gemm_kernel(const float* __restrict__ X, const float* __restrict__ M,
                     float* __restrict__ qwe)
{
  __shared__ __align__(16) float XsT[F][68];
  const int tid  = threadIdx.x;
  const int tcol = tid & 31;
  const int trow = tid >> 5;
  const long r0 = (long)blockIdx.x * 64;
  for (int idx = tid; idx < 64*F; idx += 256){
    int r = idx / F;
    int f = idx - r*F;
    XsT[f][r] = X[(r0 + r)*F + f];
  }
  __syncthreads();
  float4 acc[8];
#pragma unroll
  for (int r = 0; r < 8; ++r) acc[r] = make_float4(0.f,0.f,0.f,0.f);
  for (int f = 0; f < F; ++f){
    float4 w = *(const float4*)(&M[f*128 + 4*tcol]);
    float xs[8];
    *(float4*)&xs[0] = *(const float4*)(&XsT[f][8*trow]);
    *(float4*)&xs[4] = *(const float4*)(&XsT[f][8*trow + 4]);
#pragma unroll
    for (int r = 0; r < 8; ++r) acc[r] = f4fma(xs[r], w, acc[r]);
  }
  float4 bb = *(const float4*)(&M[F*128 + 4*tcol]);
#pragma unroll
  for (int r = 0; r < 8; ++r)
    *(float4*)(&qwe[(r0 + 8*trow + r)*128 + 4*tcol]) = f4add(acc[r], bb);
}

// ---------------- Deterministic per-graph CSR build ------------------------
__global__ __launch_bounds__(256)
void csr_build_kernel(const int* __restrict__ dstA, int npgLoc,
                      int* __restrict__ eids, int* __restrict__ rowptr,
                      int* __restrict__ deg)
{
  __shared__ int dloc[2048];
  __shared__ int ord[2048];
  __shared__ int cnt[512];
  __shared__ int base[512];
  const int g = blockIdx.x, tid = threadIdx.x;
  const int ebase = g*2048;
  const int nbase = g*npgLoc;
  for (int e = tid; e < 2048; e += 256){
    int d = dstA[ebase + e];
    dloc[e] = (d >= 0) ? (d - nbase) : -1;
  }
  for (int d = tid; d < npgLoc; d += 256) cnt[d] = 0;
  __syncthreads();
  for (int r = 0; r < 8; ++r){
    const int e = r*256 + tid;
    const int d = dloc[e];
    int rk = -1;
    if (d >= 0){
      rk = cnt[d];
      for (int u = r*256; u < e; ++u)
        rk += (dloc[u] == d);
    }
    ord[e] = rk;
    __syncthreads();
    if (d >= 0) atomicAdd(&cnt[d], 1);
    __syncthreads();
  }
  if (tid == 0){
    int run = 0;
    for (int d = 0; d < npgLoc; ++d){ base[d] = run; run += cnt[d]; }
  }
  __syncthreads();
  for (int e = tid; e < 2048; e += 256){
    int d = dloc[e];
    if (d >= 0) eids[ebase + base[d] + ord[e]] = ebase + e;
  }
  for (int d = tid; d < npgLoc; d += 256){
    rowptr[nbase + d] = ebase + base[d];
    deg   [nbase + d] = cnt[d];
  }
}

// ---------------- attn v4: ONE wave per node (all 4 heads) -----------------
// lane l: head h=l>>4, channels c=4l..4l+3 (wave covers all 256 channels).
// Score reduce = 4 shfl_xor within 16-lane head group; online softmax state
// per-lane (identical within group); no LDS, no syncthreads.
__global__ __launch_bounds__(256)
void attn_kernel(int nodeOff,
                 const float* q, const float* __restrict__ k,
                 const float* __restrict__ v, const float* __restrict__ skip,
                 const float* __restrict__ qwe,
                 const int* __restrict__ rowptr, const int* __restrict__ deg,
                 const int* __restrict__ eids, const int* __restrict__ srcA,
                 const float* __restrict__ EA, const float* __restrict__ We,
                 const float* __restrict__ Wb, float* xout)
{
  const int lane = threadIdx.x & 63;
  const int g16  = lane & 15;                 // position in head group
  const int il   = blockIdx.x*4 + (threadIdx.x >> 6);  // local node row
  const int i    = nodeOff + il;              // global node id

  float4 q4  = *(const float4*)(&q[(long)il*HC + 4*lane]);
  float2 qw2 = *(const float2*)(&qwe[(long)il*128 + 2*lane]);

  const int p0 = rowptr[i];
  const int dg = deg[i];
  int e_l = 0, s_l = 0;
  if (lane < dg){ e_l = eids[p0 + lane]; s_l = srcA[e_l] - nodeOff; }

  float m = -__builtin_inff();
  float den = 0.f;
  float4 acc = make_float4(0.f,0.f,0.f,0.f);
  float2 wsum = make_float2(0.f,0.f);

  for (int t = 0; t < dg; ++t){
    int e, s;
    if (t < 64){ e = __shfl(e_l, t); s = __shfl(s_l, t); }
    else { e = eids[p0 + t]; s = srcA[e] - nodeOff; }
    float2 ea2 = *(const float2*)(&EA[(long)e*32 + 2*g16]);
    float4 k4  = *(const float4*)(&k[(long)s*HC + 4*lane]);
    float4 v4  = *(const float4*)(&v[(long)s*HC + 4*lane]);
    float part = q4.x*k4.x + q4.y*k4.y + q4.z*k4.z + q4.w*k4.w
               + qw2.x*ea2.x + qw2.y*ea2.y;
    part += __shfl_xor(part, 1);
    part += __shfl_xor(part, 2);
    part += __shfl_xor(part, 4);
    part += __shfl_xor(part, 8);
    float alpha = part * 0.125f;
    float nm  = fmaxf(m, alpha);
    float scl = __expf(m - nm);
    float p   = __expf(alpha - nm);
    den = den*scl + p;
    acc.x = fmaf(acc.x, scl, p*v4.x);
    acc.y = fmaf(acc.y, scl, p*v4.y);
    acc.z = fmaf(acc.z, scl, p*v4.z);
    acc.w = fmaf(acc.w, scl, p*v4.w);
    wsum.x = fmaf(wsum.x, scl, p*ea2.x);
    wsum.y = fmaf(wsum.y, scl, p*ea2.y);
    m = nm;
  }

  // ecorr = (wsum over this head's 32 feats) @ We  for lane's 4 channels
  float4 ecorr = make_float4(0.f,0.f,0.f,0.f);
#pragma unroll
  for (int j = 0; j < 16; ++j){
    int srcl = (lane & 48) | j;
    float wx = __shfl(wsum.x, srcl);
    float wy = __shfl(wsum.y, srcl);
    float4 w0 = *(const float4*)(&We[(2*j)*HC + 4*lane]);
    float4 w1 = *(const float4*)(&We[(2*j+1)*HC + 4*lane]);
    ecorr = f4fma(wx, w0, ecorr);
    ecorr = f4fma(wy, w1, ecorr);
  }
  float inv = 1.f / fmaxf(den, 1e-16f);
  float4 o = make_float4((acc.x+ecorr.x)*inv, (acc.y+ecorr.y)*inv,
                         (acc.z+ecorr.z)*inv, (acc.w+ecorr.w)*inv);

  float4 xr  = *(const float4*)(&skip[(long)il*HC + 4*lane]);
  float4 wb1 = *(const float4*)(&Wb[4*lane]);
  float4 wb2 = *(const float4*)(&Wb[HC + 4*lane]);
  float4 wb3 = *(const float4*)(&Wb[2*HC + 4*lane]);
  float tp = o.x*wb1.x + o.y*wb1.y + o.z*wb1.z + o.w*wb1.w
           + xr.x*wb2.x + xr.y*wb2.y + xr.z*wb2.z + xr.w*wb2.w
           + (o.x-xr.x)*wb3.x + (o.y-xr.y)*wb3.y
           + (o.z-xr.z)*wb3.z + (o.w-xr.w)*wb3.w;
  tp += __shfl_xor(tp, 1);
  tp += __shfl_xor(tp, 2);
  tp += __shfl_xor(tp, 4);
  tp += __shfl_xor(tp, 8);
  tp += __shfl_xor(tp, 16);
  tp += __shfl_xor(tp, 32);
  float beta = 1.f / (1.f + __expf(-tp));
  float4 xo = make_float4(beta*xr.x + (1.f-beta)*o.x,
                          beta*xr.y + (1.f-beta)*o.y,
                          beta*xr.z + (1.f-beta)*o.z,
                          beta*xr.w + (1.f-beta)*o.w);
  *(float4*)(&xout[(long)il*HC + 4*lane]) = xo;
}

// ------------- y = relu(Xa[nc][256] @ Wt[256][64] + bt) --------------------
__global__ __launch_bounds__(256)
void gemm_wt_kernel(const float* __restrict__ Xa, const float* __restrict__ Wt,
                    const float* __restrict__ bt, float* __restrict__ y)
{
  __shared__ __align__(16) float XsT[64][132];
  const int tid  = threadIdx.x;
  const int tcol = tid & 15;
  const int trow = tid >> 4;
  const long r0 = (long)blockIdx.x * 128;
  float4 acc[8];
#pragma unroll
  for (int r = 0; r < 8; ++r) acc[r] = make_float4(0.f,0.f,0.f,0.f);
  for (int kc = 0; kc < 4; ++kc){
    for (int idx = tid; idx < 128*64; idx += 256){
      int r = idx >> 6;
      int f = idx & 63;
      XsT[f][r] = Xa[(r0 + r)*HC + kc*64 + f];
    }
    __syncthreads();
    for (int f = 0; f < 64; ++f){
      float4 w = *(const float4*)(&Wt[(kc*64 + f)*64 + 4*tcol]);
      float xs[8];
      *(float4*)&xs[0] = *(const float4*)(&XsT[f][8*trow]);
      *(float4*)&xs[4] = *(const float4*)(&XsT[f][8*trow + 4]);
#pragma unroll
      for (int r = 0; r < 8; ++r) acc[r] = f4fma(xs[r], w, acc[r]);
    }
    __syncthreads();
  }
  float4 bb = *(const float4*)(&bt[4*tcol]);
#pragma unroll
  for (int r = 0; r < 8; ++r){
    float4 o = f4add(acc[r], bb);
    o.x = fmaxf(o.x, 0.f); o.y = fmaxf(o.y, 0.f);
    o.z = fmaxf(o.z, 0.f); o.w = fmaxf(o.w, 0.f);
    *(float4*)(&y[(r0 + 8*trow + r)*64 + 4*tcol]) = o;
  }
}

// ------------- BN stats: 256-block grid-stride partials --------------------
__global__ __launch_bounds__(256)
void bn_stats_kernel(const float* __restrict__ y, long total4,
                     float* __restrict__ psum, float* __restrict__ psq)
{
  __shared__ float s1[256][4], s2[256][4];
  const int tid = threadIdx.x;
  float a0=0,a1=0,a2=0,a3=0,b0=0,b1=0,b2=0,b3=0;
  const float4* y4 = (const float4*)y;
  for (long j = (long)blockIdx.x*256 + tid; j < total4; j += 65536){
    float4 v = y4[j];
    a0 += v.x; b0 += v.x*v.x;
    a1 += v.y; b1 += v.y*v.y;
    a2 += v.z; b2 += v.z*v.z;
    a3 += v.w; b3 += v.w*v.w;
  }
  s1[tid][0]=a0; s1[tid][1]=a1; s1[tid][2]=a2; s1[tid][3]=a3;
  s2[tid][0]=b0; s2[tid][1]=b1; s2[tid][2]=b2; s2[tid][3]=b3;
  __syncthreads();
  if (tid < 64){
    int t0 = tid >> 2, comp = tid & 3;
    float sa = 0.f, sb = 0.f;
#pragma unroll
    for (int kk = 0; kk < 16; ++kk){
      sa += s1[t0 + 16*kk][comp];
      sb += s2[t0 + 16*kk][comp];
    }
    psum[(long)blockIdx.x*64 + tid] = sa;
    psq [(long)blockIdx.x*64 + tid] = sb;
  }
}

__global__ void bn_finalize_kernel(const float* __restrict__ psum,
                                   const float* __restrict__ psq,
                                   float n_f, float* musd)
{
  __shared__ float s1[4][64], s2[4][64];
  const int col = threadIdx.x & 63;
  const int part = threadIdx.x >> 6;
  float a = 0.f, b = 0.f;
  for (int j = part; j < 256; j += 4){
    a += psum[(long)j*64 + col];
    b += psq [(long)j*64 + col];
  }
  s1[part][col] = a; s2[part][col] = b;
  __syncthreads();
  if (threadIdx.x < 64){
    int c = threadIdx.x;
    float sa = s1[0][c] + s1[1][c] + s1[2][c] + s1[3][c];
    float sb = s2[0][c] + s2[1][c] + s2[2][c] + s2[3][c];
    float mu = sa / n_f;
    float var = sb / n_f - mu*mu;
    musd[c] = mu;
    musd[64 + c] = rsqrtf(var + 1e-5f);
  }
}

__global__ void bn_apply_kernel(float* y, const float* __restrict__ musd,
                                const float* __restrict__ g,
                                const float* __restrict__ b, long total)
{
  long i4 = ((long)blockIdx.x * 256 + threadIdx.x) * 4;
  if (i4 >= total) return;
  int c0 = (int)(i4 & 63);
  float4 yv = *(float4*)&y[i4];
  yv.x = (yv.x - musd[c0+0]) * musd[64+c0+0] * g[c0+0] + b[c0+0];
  yv.y = (yv.y - musd[c0+1]) * musd[64+c0+1] * g[c0+1] + b[c0+1];
  yv.z = (yv.z - musd[c0+2]) * musd[64+c0+2] * g[c0+2] + b[c0+2];
  yv.w = (yv.w - musd[c0+3]) * musd[64+c0+3] * g[c0+3] + b[c0+3];
  *(float4*)&y[i4] = yv;
}

// ---------------- TopK pooling: exact rank (ties by lower index) -----------
__global__ __launch_bounds__(256)
void topk_kernel(const float* __restrict__ x, const float* __restrict__ pw,
                 float* __restrict__ x2, int* __restrict__ newidx,
                 int npg, int kkeep)
{
  __shared__ float sc[512];
  __shared__ float wS[64];
  const int g = blockIdx.x, tid = threadIdx.x;
  if (tid < 64) wS[tid] = pw[tid];
  __syncthreads();
  float nrm = 0.f;
#pragma unroll
  for (int c = 0; c < 64; ++c) nrm += wS[c]*wS[c];
  nrm = sqrtf(nrm);
  for (int il = tid; il < npg; il += 256){
    const float* xr = x + (long)(g*npg + il)*64;
    float d = 0.f;
    for (int c = 0; c < 64; ++c) d = fmaf(xr[c], wS[c], d);
    sc[il] = tanhf(d / nrm);
  }
  __syncthreads();
  for (int il = tid; il < npg; il += 256){
    float si = sc[il];
    int r = 0;
    for (int j = 0; j < npg; ++j){
      float sj = sc[j];
      r += (sj > si) || (sj == si && j < il);
    }
    int gi = g*npg + il;
    if (r < kkeep){
      int npos = g*kkeep + r;
      newidx[gi] = npos;
      const float4* xr4 = (const float4*)(x + (long)gi*64);
      float4* xo4 = (float4*)(x2 + (long)npos*64);
#pragma unroll
      for (int c4 = 0; c4 < 16; ++c4){
        float4 xv = xr4[c4];
        xo4[c4] = make_float4(xv.x*si, xv.y*si, xv.z*si, xv.w*si);
      }
    } else {
      newidx[gi] = -1;
    }
  }
}

__global__ void remap_kernel(const int* __restrict__ src0, const int* __restrict__ dst0,
                             const int* __restrict__ newidx,
                             int* __restrict__ src2, int* __restrict__ dst2)
{
  int e = blockIdx.x * 256 + threadIdx.x;
  int ns = newidx[src0[e]];
  int nd = newidx[dst0[e]];
  bool ok = (ns >= 0) && (nd >= 0);
  src2[e] = ok ? ns : 0;
  dst2[e] = ok ? nd : -1;
}

// ---------------- Graph readout: max + mean (f32 output) -------------------
__global__ void gpool_kernel(const float* __restrict__ x2, int kkeep,
                             float* grep0, float* out, int mode)
{
  const int g = blockIdx.x, c = threadIdx.x;   // 64 threads
  float mx = -__builtin_inff(), s = 0.f;
  for (int j = 0; j < kkeep; ++j){
    float vv = x2[((long)g*kkeep + j)*64 + c];
    mx = fmaxf(mx, vv);
    s += vv;
  }
  float mean = s / (float)kkeep;
  if (mode == 0){
    grep0[g*128 + c] = mx;
    grep0[g*128 + 64 + c] = mean;
  } else {
    out[g*128 + c]      = grep0[g*128 + c] + mx;
    out[g*128 + 64 + c] = grep0[g*128 + 64 + c] + mean;
  }
}

// ---------------------------------------------------------------------------
extern "C" void kernel_launch(void* const* d_in, const int* in_sizes, int n_in,
                              void* d_out, int out_size, void* d_ws, size_t ws_size,
                              hipStream_t stream)
{
  const float* x_in = (const float*)d_in[0];
  const float* EA   = (const float*)d_in[1];
  const int*   eidx = (const int*)d_in[2];
  const int*   src0 = eidx;
  const int*   dst0 = eidx + NE;

  const float* Wq1    = (const float*)d_in[4];
  const float* bq1    = (const float*)d_in[5];
  const float* Wk1    = (const float*)d_in[6];
  const float* bk1    = (const float*)d_in[7];
  const float* Wv1    = (const float*)d_in[8];
  const float* bv1    = (const float*)d_in[9];
  const float* We1    = (const float*)d_in[10];
  const float* Wskip1 = (const float*)d_in[11];
  const float* bskip1 = (const float*)d_in[12];
  const float* Wbeta1 = (const float*)d_in[13];
  const float* Wt1    = (const float*)d_in[14];
  const float* bt1    = (const float*)d_in[15];
  const float* bng1   = (const float*)d_in[16];
  const float* bnb1   = (const float*)d_in[17];
  const float* WqL    = (const float*)d_in[18];
  const float* bqL    = (const float*)d_in[19];
  const float* WkL    = (const float*)d_in[20];
  const float* bkL    = (const float*)d_in[21];
  const float* WvL    = (const float*)d_in[22];
  const float* bvL    = (const float*)d_in[23];
  const float* WeL    = (const float*)d_in[24];
  const float* WskipL = (const float*)d_in[25];
  const float* bskipL = (const float*)d_in[26];
  const float* WbetaL = (const float*)d_in[27];
  const float* WtL    = (const float*)d_in[28];
  const float* btL    = (const float*)d_in[29];
  const float* bngL   = (const float*)d_in[30];
  const float* bnbL   = (const float*)d_in[31];
  const float* pw0    = (const float*)d_in[32];
  const float* pw2    = (const float*)d_in[33];

  // ---- adaptive chunking: q/k/v/skip (n x 256) + qwe (n x 128) -----------
  const size_t FIXED = 33554432ull;
  int chunks = 1;
  while (chunks < 32 && 9ull*(67108864ull/chunks)/2 + FIXED > ws_size)
    chunks <<= 1;
  const int gpc = NGRAPH / chunks;           // graphs per chunk
  const size_t C = 67108864ull / chunks;     // bytes per 256-wide buffer
  const long CF = (long)(C / 4);             // floats per 256-wide buffer

  char* wsb = (char*)d_ws;
  float* qb   = (float*)(wsb);
  float* kb   = (float*)(wsb + C);
  float* vb   = (float*)(wsb + 2*C);
  float* sk   = (float*)(wsb + 3*C);
  float* qweb = (float*)(wsb + 4*C);         // C/2 bytes
  char* p = wsb + 4*C + C/2;
  auto alloc = [&](size_t bytes){ char* r = p; p += (bytes + 255) & ~255ull; return r; };
  float* y      = (float*)alloc(16777216ull);
  float* x2     = (float*)alloc(8388608ull);
  float* ps     = (float*)alloc(65536ull);
  float* pq     = (float*)alloc(65536ull);
  float* musd   = (float*)alloc(4096ull);
  float* grep0  = (float*)alloc(65536ull);
  float* Mbuf   = (float*)alloc(66304ull);
  int* newidx   = (int*)alloc(262144ull);
  int* src2     = (int*)alloc(1048576ull);
  int* dst2     = (int*)alloc(1048576ull);
  int* eidsA    = (int*)alloc(1048576ull);
  int* rowptrA  = (int*)alloc(262144ull);
  int* degA     = (int*)alloc(262144ull);
  int* eidsB    = (int*)alloc(1048576ull);
  int* rowptrB  = (int*)alloc(131072ull);
  int* degB     = (int*)alloc(131072ull);

  // -------- CSR for full topology --------
  csr_build_kernel<<<NGRAPH, 256, 0, stream>>>(dst0, 512, eidsA, rowptrA, degA);

  // -------- Layer 1 (F=128, n=65536, npg=512) --------
  {
    const int npg = 512, n = NTOT;
    mcomb_kernel<<<(129*128 + 255)/256, 256, 0, stream>>>(Wq1, bq1, We1, 128, Mbuf);
    for (int c = 0; c < chunks; ++c){
      const int nOff = c * gpc * npg;
      const int nc   = gpc * npg;
      const float* Xc = x_in + (long)nOff * 128;
      dim3 grid(nc/32, 4);
      gemm_qkvs_kernel<128><<<grid, 256, 0, stream>>>(
          Xc, Wq1, bq1, Wk1, bk1, Wv1, bv1, Wskip1, bskip1, qb, CF);
      qwe_gemm_kernel<128><<<nc/64, 256, 0, stream>>>(Xc, Mbuf, qweb);
      attn_kernel<<<nc/4, 256, 0, stream>>>(nOff, qb, kb, vb, sk, qweb,
          rowptrA, degA, eidsA, src0, EA, We1, Wbeta1, qb);
      gemm_wt_kernel<<<nc/128, 256, 0, stream>>>(qb, Wt1, bt1, y + (long)nOff*64);
    }
    bn_stats_kernel<<<256, 256, 0, stream>>>(y, (long)n*16, ps, pq);
    bn_finalize_kernel<<<1, 256, 0, stream>>>(ps, pq, (float)n, musd);
    bn_apply_kernel<<<n/16, 256, 0, stream>>>(y, musd, bng1, bnb1, (long)n*64);
  }

  // -------- Loop layers i = 0..2 --------
  for (int i = 0; i < 3; ++i){
    const int n   = (i == 0) ? NTOT : NTOT/2;
    const int npg = (i == 0) ? 512 : 256;
    const float* xin = (i == 0) ? y : ((i == 1) ? x2 : y);
    const int* rp = (i == 0) ? rowptrA : rowptrB;
    const int* dgp= (i == 0) ? degA    : degB;
    const int* ei = (i == 0) ? eidsA   : eidsB;
    const int* sA = (i == 0) ? src0    : src2;
    const float* Wq_ = WqL + (long)i*64*256;  const float* bq_ = bqL + i*256;
    const float* Wk_ = WkL + (long)i*64*256;  const float* bk_ = bkL + i*256;
    const float* Wv_ = WvL + (long)i*64*256;  const float* bv_ = bvL + i*256;
    const float* Ws_ = WskipL + (long)i*64*256; const float* bs_ = bskipL + i*256;
    const float* We_ = WeL + (long)i*32*256;
    const float* Wb_ = WbetaL + i*768;
    const float* Wt_ = WtL + (long)i*256*64;  const float* bt_ = btL + i*64;
    const float* g_  = bngL + i*64;           const float* b_  = bnbL + i*64;

    mcomb_kernel<<<(65*128 + 255)/256, 256, 0, stream>>>(Wq_, bq_, We_, 64, Mbuf);
    for (int c = 0; c < chunks; ++c){
      const int nOff = c * gpc * npg;
      const int nc   = gpc * npg;
      const float* Xc = xin + (long)nOff * 64;
      dim3 grid(nc/32, 4);
      gemm_qkvs_kernel<64><<<grid, 256, 0, stream>>>(
          Xc, Wq_, bq_, Wk_, bk_, Wv_, bv_, Ws_, bs_, qb, CF);
      qwe_gemm_kernel<64><<<nc/64, 256, 0, stream>>>(Xc, Mbuf, qweb);
      attn_kernel<<<nc/4, 256, 0, stream>>>(nOff, qb, kb, vb, sk, qweb,
          rp, dgp, ei, sA, EA, We_, Wb_, qb);
      gemm_wt_kernel<<<nc/128, 256, 0, stream>>>(qb, Wt_, bt_, y + (long)nOff*64);
    }
    bn_stats_kernel<<<256, 256, 0, stream>>>(y, (long)n*16, ps, pq);
    bn_finalize_kernel<<<1, 256, 0, stream>>>(ps, pq, (float)n, musd);
    bn_apply_kernel<<<n/16, 256, 0, stream>>>(y, musd, g_, b_, (long)n*64);

    if (i == 0){
      topk_kernel<<<NGRAPH, 256, 0, stream>>>(y, pw0, x2, newidx, 512, 256);
      remap_kernel<<<NE/256, 256, 0, stream>>>(src0, dst0, newidx, src2, dst2);
      csr_build_kernel<<<NGRAPH, 256, 0, stream>>>(dst2, 256, eidsB, rowptrB, degB);
      gpool_kernel<<<NGRAPH, 64, 0, stream>>>(x2, 256, grep0, (float*)d_out, 0);
    } else if (i == 2){
      topk_kernel<<<NGRAPH, 256, 0, stream>>>(y, pw2, x2, newidx, 256, 128);
      gpool_kernel<<<NGRAPH, 64, 0, stream>>>(x2, 128, grep0, (float*)d_out, 1);
    }
  }

  (void)in_sizes; (void)n_in; (void)out_size; (void)ws_size;
}